// Round 8
// baseline (3032.227 us; speedup 1.0000x reference)
//
#include <hip/hip_runtime.h>
#include <hip/hip_bf16.h>
#include <math.h>

#define BB 4
#define TT 2048
#define VV 99
#define DD 512
#define HH 8
#define LL 6
#define DHH 64
#define OFFS 28
#define ROWS (BB*TT)   // 8192

typedef __hip_bfloat16 bf16;
typedef __attribute__((ext_vector_type(8))) short bf16x8;
typedef __attribute__((ext_vector_type(4))) float f32x4;

__device__ __forceinline__ float b2f(bf16 x){ return __bfloat162float(x); }

// mode-dispatched weight read from a raw base + element offset (mode1 = bf16 inputs)
__device__ __forceinline__ float wget(const void* w, int mode, size_t i){
    return mode ? b2f(((const bf16*)w)[i]) : ((const float*)w)[i];
}

// ---------------- init ----------------
__global__ void init_kernel(const unsigned int* __restrict__ ln1_bits, float* __restrict__ acc,
                            int* __restrict__ flag){
    acc[0] = 0.f; acc[1] = 0.f;
    flag[0] = (ln1_bits[0] == 0x3F800000u) ? 0 : 1;
}

// ---------------- embedding ----------------
__global__ void embed_kernel(const int* __restrict__ idx, const void* __restrict__ wte,
                             const void* __restrict__ wpe, float* __restrict__ x,
                             const int* __restrict__ flag){
    int mode = flag[0];
    int row = blockIdx.x;
    int t = row % TT;
    int tok = idx[row];
    int i = threadIdx.x;
    #pragma unroll
    for (int j = 0; j < 2; ++j){
        int d = i + j*256;
        x[(size_t)row*DD + d] = wget(wte, mode, (size_t)tok*DD + d)
                              + wget(wpe, mode, (size_t)t*DD + d);
    }
}

// ---------------- layernorm: fp32 in, bf16 out ----------------
__global__ void ln_kernel(const float* __restrict__ x, const void* __restrict__ w,
                          size_t woff, bf16* __restrict__ out, const int* __restrict__ flag){
    int mode = flag[0];
    int row = blockIdx.x;
    int lane = threadIdx.x; // 64
    const float* xr = x + (size_t)row*DD;
    float v[8];
    float s = 0.f;
    #pragma unroll
    for (int j=0;j<8;++j){ v[j] = xr[lane + j*64]; s += v[j]; }
    #pragma unroll
    for (int o=32;o;o>>=1) s += __shfl_xor(s,o);
    float mean = s * (1.0f/DD);
    float vs = 0.f;
    #pragma unroll
    for (int j=0;j<8;++j){ float d = v[j]-mean; vs += d*d; }
    #pragma unroll
    for (int o=32;o;o>>=1) vs += __shfl_xor(vs,o);
    float rstd = rsqrtf(vs*(1.0f/DD) + 1e-5f);
    #pragma unroll
    for (int j=0;j<8;++j){
        int d = lane + j*64;
        out[(size_t)row*DD + d] = __float2bfloat16((v[j]-mean)*rstd*wget(w,mode,woff+d));
    }
}

// ---------------- MFMA GEMM: C[M,N] = A[M,K] @ W[N,K]^T ----------------
// 128x128 tile, BK=32, 4 waves x (4x4) 16x16x32 bf16 MFMA frags.
// EPI: 0 = bf16 store Cb, 1 = fp32 += C (residual), 2 = gelu -> bf16 Cb
template<int EPI>
__global__ __launch_bounds__(256) void gemm_mfma(const bf16* __restrict__ A,
        const void* __restrict__ W, size_t woff, float* __restrict__ C, bf16* __restrict__ Cb,
        int M, int N, int K, const int* __restrict__ flag){
    int mode = flag[0];
    __shared__ short As[128*32];
    __shared__ short Ws[128*32];
    int tid = threadIdx.x;
    int m0 = blockIdx.y * 128;
    int n0 = blockIdx.x * 128;
    int lane = tid & 63, wave = tid >> 6;
    int wm = (wave & 1) * 64, wn = (wave >> 1) * 64;
    int quad = lane >> 4, l16 = lane & 15;

    f32x4 acc[4][4] = {};

    int ra = tid >> 1;
    int ha = (tid & 1) * 16;

    for (int k0 = 0; k0 < K; k0 += 32){
        __syncthreads();
        {
            const uint4* gp = (const uint4*)(A + (size_t)(m0+ra)*K + k0 + ha);
            uint4 v0 = gp[0], v1 = gp[1];
            *(uint4*)&As[ra*32 + ha]     = v0;
            *(uint4*)&As[ra*32 + ha + 8] = v1;
        }
        if (mode == 0){
            const float4* wp = (const float4*)((const float*)W + woff + (size_t)(n0+ra)*K + k0 + ha);
            float4 f0 = wp[0], f1 = wp[1], f2 = wp[2], f3 = wp[3];
            union { short s[16]; uint4 u[2]; } cv;
            float tmp[16] = {f0.x,f0.y,f0.z,f0.w, f1.x,f1.y,f1.z,f1.w,
                             f2.x,f2.y,f2.z,f2.w, f3.x,f3.y,f3.z,f3.w};
            #pragma unroll
            for (int k=0;k<16;++k) cv.s[k] = __bfloat16_as_short(__float2bfloat16(tmp[k]));
            *(uint4*)&Ws[ra*32 + ha]     = cv.u[0];
            *(uint4*)&Ws[ra*32 + ha + 8] = cv.u[1];
        } else {
            const uint4* wp = (const uint4*)((const bf16*)W + woff + (size_t)(n0+ra)*K + k0 + ha);
            uint4 v0 = wp[0], v1 = wp[1];
            *(uint4*)&Ws[ra*32 + ha]     = v0;
            *(uint4*)&Ws[ra*32 + ha + 8] = v1;
        }
        __syncthreads();

        bf16x8 af[4], bf[4];
        #pragma unroll
        for (int mi=0;mi<4;++mi)
            af[mi] = *(const bf16x8*)&As[(wm + mi*16 + l16)*32 + quad*8];
        #pragma unroll
        for (int ni=0;ni<4;++ni)
            bf[ni] = *(const bf16x8*)&Ws[(wn + ni*16 + l16)*32 + quad*8];
        #pragma unroll
        for (int mi=0;mi<4;++mi)
            #pragma unroll
            for (int ni=0;ni<4;++ni)
                acc[mi][ni] = __builtin_amdgcn_mfma_f32_16x16x32_bf16(af[mi], bf[ni], acc[mi][ni], 0, 0, 0);
    }

    #pragma unroll
    for (int mi=0;mi<4;++mi){
        #pragma unroll
        for (int ni=0;ni<4;++ni){
            int mg = m0 + wm + mi*16 + quad*4;
            int ng = n0 + wn + ni*16 + l16;
            #pragma unroll
            for (int reg=0;reg<4;++reg){
                float val = acc[mi][ni][reg];
                size_t off = (size_t)(mg+reg)*N + ng;
                if (EPI==0){
                    Cb[off] = __float2bfloat16(val);
                } else if (EPI==1){
                    C[off] += val;
                } else {
                    float xx = val;
                    float u = 0.7978845608028654f*(xx + 0.044715f*xx*xx*xx);
                    Cb[off] = __float2bfloat16(0.5f*xx*(1.0f+tanhf(u)));
                }
            }
        }
    }
}

// ---------------- VALU GEMM (kept for logits: N=99), fp32 store ----------------
__global__ __launch_bounds__(256) void gemm_nt3(const bf16* __restrict__ A,
        const void* __restrict__ W, size_t woff, float* __restrict__ C,
        int M, int N, int K, const int* __restrict__ flag){
    int mode = flag[0];
    __shared__ float As[16][64];
    __shared__ float Wt[16][64];
    int m0 = blockIdx.y * 64;
    int n0 = blockIdx.x * 64;
    int t = threadIdx.x;
    int tx = t & 15, ty = t >> 4;
    float acc[4][4] = {};
    int am = t >> 2;
    int ak = (t & 3) * 4;

    for (int k0 = 0; k0 < K; k0 += 16){
        {
            const __hip_bfloat162* ap = (const __hip_bfloat162*)(A + (size_t)(m0+am)*K + k0 + ak);
            __hip_bfloat162 p0 = ap[0], p1 = ap[1];
            float2 f0 = __bfloat1622float2(p0), f1 = __bfloat1622float2(p1);
            As[ak+0][am]=f0.x; As[ak+1][am]=f0.y; As[ak+2][am]=f1.x; As[ak+3][am]=f1.y;
        }
        int wn = n0 + am;
        if (wn < N){
            size_t off = woff + (size_t)wn*K + k0 + ak;
            if (mode == 0){
                float4 wv = *(const float4*)((const float*)W + off);
                Wt[ak+0][am]=wv.x; Wt[ak+1][am]=wv.y; Wt[ak+2][am]=wv.z; Wt[ak+3][am]=wv.w;
            } else {
                const __hip_bfloat162* wp = (const __hip_bfloat162*)((const bf16*)W + off);
                __hip_bfloat162 p0 = wp[0], p1 = wp[1];
                float2 f0 = __bfloat1622float2(p0), f1 = __bfloat1622float2(p1);
                Wt[ak+0][am]=f0.x; Wt[ak+1][am]=f0.y; Wt[ak+2][am]=f1.x; Wt[ak+3][am]=f1.y;
            }
        } else {
            Wt[ak+0][am]=0.f; Wt[ak+1][am]=0.f; Wt[ak+2][am]=0.f; Wt[ak+3][am]=0.f;
        }
        __syncthreads();
        #pragma unroll
        for (int kk=0;kk<16;++kk){
            float a[4], b[4];
            #pragma unroll
            for (int i=0;i<4;++i) a[i]=As[kk][ty*4+i];
            #pragma unroll
            for (int j=0;j<4;++j) b[j]=Wt[kk][tx*4+j];
            #pragma unroll
            for (int i=0;i<4;++i)
                #pragma unroll
                for (int j=0;j<4;++j)
                    acc[i][j] += a[i]*b[j];
        }
        __syncthreads();
    }

    #pragma unroll
    for (int i=0;i<4;++i){
        int m = m0 + ty*4 + i;
        #pragma unroll
        for (int j=0;j<4;++j){
            int n = n0 + tx*4 + j;
            if (n >= N) continue;
            C[(size_t)m*N+n] = acc[i][j];
        }
    }
}

// ---------------- V transpose: qkv V-part -> VT [b][h][d][T] bf16 ----------------
__global__ __launch_bounds__(256) void vtrans_kernel(const bf16* __restrict__ qkv,
                                                     bf16* __restrict__ VT){
    __shared__ short Lt[64*72];
    int tid = threadIdx.x;
    int jt = blockIdx.x;      // 0..31
    int bh = blockIdx.y;      // 0..31 = b*8+h
    int h = bh & 7, b = bh >> 3;
    int j0 = jt*64;
    int r = tid >> 2, dc = (tid & 3) << 4;
    const uint4* gp = (const uint4*)(qkv + (size_t)(b*TT + j0 + r)*1536 + 2*DD + h*64 + dc);
    uint4 v0 = gp[0], v1 = gp[1];
    short tmp[16];
    *(uint4*)&tmp[0] = v0; *(uint4*)&tmp[8] = v1;
    #pragma unroll
    for (int k=0;k<16;++k) Lt[(dc+k)*72 + r] = tmp[k];
    __syncthreads();
    uint4 o0 = *(uint4*)&Lt[r*72 + dc];
    uint4 o1 = *(uint4*)&Lt[r*72 + dc + 8];
    uint4* op = (uint4*)(VT + ((size_t)bh*64 + r)*TT + j0 + dc);
    op[0] = o0; op[1] = o1;
}

// ---------------- attention v4: barrier-free MFMA flash ----------------
// One wg = 4 independent waves; wave handles 16 q rows of (b,h,qtile64).
// Q/K frags direct from global qkv; V frags direct from global VT; P via 1.3KB/wave LDS.
#define PST 40
__global__ __launch_bounds__(256) void attn_flash(const bf16* __restrict__ qkv,
                                                  const bf16* __restrict__ VT,
                                                  bf16* __restrict__ y){
    __shared__ short Ps[4*16*PST];
    int tid = threadIdx.x;
    int lane = tid & 63, wave = tid >> 6;
    int quad = lane >> 4, l16 = lane & 15;
    int bi = blockIdx.x;
    int qt = 31 - (bi & 31);
    int bh = bi >> 5;
    int h = bh & 7, b = bh >> 3;
    int q0 = qt * 64 + wave * 16;           // wave's q base
    size_t base = (size_t)b * TT * 1536;

    // Q A-frags straight from global (A[m=l16][k=quad*8+i] = Q row-major)
    const bf16* qrow = qkv + base + (size_t)(q0 + l16)*1536 + h*64;
    bf16x8 aq0 = *(const bf16x8*)(qrow + quad*8);
    bf16x8 aq1 = *(const bf16x8*)(qrow + 32 + quad*8);

    f32x4 O[4] = {};
    float mr[4] = {-1e30f,-1e30f,-1e30f,-1e30f};
    float lr[4] = {0.f,0.f,0.f,0.f};

    short* pw = &Ps[wave*16*PST];
    const bf16* kbase = qkv + base + DD + h*64;
    const bf16* vtb   = VT + (size_t)bh*64*TT;

    int jmax = q0 + 15 + OFFS; if (jmax > TT-1) jmax = TT-1;
    for (int j0 = 0; j0 <= jmax; j0 += 32){
        bool bd = (j0 + 31 > q0 + OFFS) || (j0 + 31 > TT-1);
        // S = Q K^T (16q x 32j): K B-frags direct from global (row-major)
        f32x4 s[2];
        #pragma unroll
        for (int ni=0; ni<2; ++ni){
            int jr = j0 + ni*16 + l16; if (jr > TT-1) jr = TT-1;
            const bf16* kp = kbase + (size_t)jr*1536;
            bf16x8 bk0 = *(const bf16x8*)(kp + quad*8);
            bf16x8 bk1 = *(const bf16x8*)(kp + 32 + quad*8);
            f32x4 z = {};
            z = __builtin_amdgcn_mfma_f32_16x16x32_bf16(aq0, bk0, z, 0, 0, 0);
            z = __builtin_amdgcn_mfma_f32_16x16x32_bf16(aq1, bk1, z, 0, 0, 0);
            s[ni] = z;
        }
        // scale + mask (C-layout: row=quad*4+reg, col=ni*16+l16)
        float sc[2][4];
        #pragma unroll
        for (int ni=0; ni<2; ++ni){
            #pragma unroll
            for (int reg=0; reg<4; ++reg){
                float v = s[ni][reg] * 0.125f;
                if (bd){
                    int qg = q0 + quad*4 + reg;
                    int jg = j0 + ni*16 + l16;
                    if (jg > qg + OFFS || jg > TT-1) v = -1e30f;
                }
                sc[ni][reg] = v;
            }
        }
        // online softmax
        float bm[4], alpha[4], rs[4];
        #pragma unroll
        for (int reg=0; reg<4; ++reg) bm[reg] = fmaxf(sc[0][reg], sc[1][reg]);
        #pragma unroll
        for (int o=1;o<16;o<<=1){
            #pragma unroll
            for (int reg=0; reg<4; ++reg) bm[reg] = fmaxf(bm[reg], __shfl_xor(bm[reg], o));
        }
        #pragma unroll
        for (int reg=0; reg<4; ++reg){
            float nm = fmaxf(mr[reg], bm[reg]);
            alpha[reg] = __expf(mr[reg] - nm);
            mr[reg] = nm;
            sc[0][reg] = __expf(sc[0][reg] - nm);
            sc[1][reg] = __expf(sc[1][reg] - nm);
            rs[reg] = sc[0][reg] + sc[1][reg];
        }
        #pragma unroll
        for (int o=1;o<16;o<<=1){
            #pragma unroll
            for (int reg=0; reg<4; ++reg) rs[reg] += __shfl_xor(rs[reg], o);
        }
        #pragma unroll
        for (int reg=0; reg<4; ++reg){
            lr[reg] = lr[reg]*alpha[reg] + rs[reg];
            #pragma unroll
            for (int dt=0; dt<4; ++dt) O[dt][reg] *= alpha[reg];
        }
        // P: C-layout -> A-layout via per-wave LDS (no cross-wave hazard, no barrier)
        #pragma unroll
        for (int ni=0; ni<2; ++ni)
            #pragma unroll
            for (int reg=0; reg<4; ++reg)
                pw[(quad*4+reg)*PST + ni*16 + l16] =
                    __bfloat16_as_short(__float2bfloat16(sc[ni][reg]));
        bf16x8 ap = *(const bf16x8*)&pw[l16*PST + quad*8];
        // O += P V : V B-frags direct from global VT (row-major in j)
        #pragma unroll
        for (int dt=0; dt<4; ++dt){
            bf16x8 bv = *(const bf16x8*)(vtb + (size_t)(dt*16 + l16)*TT + j0 + quad*8);
            O[dt] = __builtin_amdgcn_mfma_f32_16x16x32_bf16(ap, bv, O[dt], 0, 0, 0);
        }
    }

    // epilogue
    float inv[4];
    #pragma unroll
    for (int reg=0; reg<4; ++reg) inv[reg] = 1.0f / lr[reg];
    #pragma unroll
    for (int dt=0; dt<4; ++dt){
        #pragma unroll
        for (int reg=0; reg<4; ++reg){
            int qg = q0 + quad*4 + reg;
            y[((size_t)b*TT + qg)*DD + h*64 + dt*16 + l16] =
                __float2bfloat16(O[dt][reg] * inv[reg]);
        }
    }
}

// ---------------- loss (fp32 logits) ----------------
__global__ void loss_kernel(const float* __restrict__ logits, const int* __restrict__ targets,
                            float* __restrict__ acc){
    int row = blockIdx.x;
    int lane = threadIdx.x;
    int yt = targets[row];
    const float* lp = logits + (size_t)row*VV;
    float e0 = (lane < VV)    ? lp[lane]    : -1e30f;
    float e1 = (lane+64 < VV) ? lp[lane+64] : -1e30f;
    float mx = fmaxf(e0,e1);
    #pragma unroll
    for (int o=32;o;o>>=1) mx = fmaxf(mx, __shfl_xor(mx,o));
    float se = 0.f;
    if (lane < VV)    se += __expf(e0-mx);
    if (lane+64 < VV) se += __expf(e1-mx);
    #pragma unroll
    for (int o=32;o;o>>=1) se += __shfl_xor(se,o);
    if (lane == 0 && yt >= 0){
        float wi = (yt>=78 && yt<96) ? 1.0f : (yt==96 ? 0.1f : 0.0f);
        if (wi > 0.f){
            float ly = lp[yt];
            float nll = -(ly - mx - logf(se));
            atomicAdd(&acc[0], wi*nll);
            atomicAdd(&acc[1], wi);
        }
    }
}

__global__ void fin_loss(const float* __restrict__ acc, float* __restrict__ out){
    out[0] = acc[0]/acc[1];
}

// ---------------- launch ----------------
extern "C" void kernel_launch(void* const* d_in, const int* in_sizes, int n_in,
                              void* d_out, int out_size, void* d_ws, size_t ws_size,
                              hipStream_t stream){
    const int*  idx     = (const int*) d_in[0];
    const int*  targets = (const int*) d_in[1];
    const void* wte     = d_in[2];
    const void* wpe     = d_in[3];
    const void* ln1_w   = d_in[4];
    const void* attn_w  = d_in[5];
    const void* proj_w  = d_in[6];
    const void* ln2_w   = d_in[7];
    const void* fc_w    = d_in[8];
    const void* fcp_w   = d_in[9];
    const void* lnf_w   = d_in[10];
    float* out = (float*)d_out;   // fp32: logits [8192,99] then loss [1]

    float* ws   = (float*)d_ws;
    float* ACC  = ws;
    int*   FLAG = (int*)(ws + 4);
    bf16*  Hb   = (bf16*)(ws + 16);                                  // [8192,512] bf16 (8MB)
    float* X    = ws + 16 + 2097152;                                 // [8192,512] fp32 (16MB)
    bf16*  BIG  = (bf16*)(ws + 16 + 2097152 + 4194304);              // [8192,2048] bf16 (32MB)
    bf16*  VT   = (bf16*)(ws + 16 + 2097152 + 4194304 + 8388608);    // [32][64][2048] bf16 (16MB)

    const size_t ATT_S = (size_t)3*DD*DD;
    const size_t PRJ_S = (size_t)DD*DD;
    const size_t FC_S  = (size_t)4*DD*DD;

    init_kernel<<<1,1,0,stream>>>((const unsigned int*)ln1_w, ACC, FLAG);
    embed_kernel<<<ROWS,256,0,stream>>>(idx, wte, wpe, X, FLAG);
    for (int l=0; l<LL; ++l){
        ln_kernel<<<ROWS,64,0,stream>>>(X, ln1_w, (size_t)l*DD, Hb, FLAG);
        gemm_mfma<0><<<dim3(3*DD/128, ROWS/128),256,0,stream>>>(Hb, attn_w, (size_t)l*ATT_S,
                                                                nullptr, BIG, ROWS, 3*DD, DD, FLAG);
        vtrans_kernel<<<dim3(32,32),256,0,stream>>>(BIG, VT);
        attn_flash<<<dim3(BB*HH*32),256,0,stream>>>(BIG, VT, Hb);
        gemm_mfma<1><<<dim3(DD/128, ROWS/128),256,0,stream>>>(Hb, proj_w, (size_t)l*PRJ_S,
                                                              X, nullptr, ROWS, DD, DD, FLAG);
        ln_kernel<<<ROWS,64,0,stream>>>(X, ln2_w, (size_t)l*DD, Hb, FLAG);
        gemm_mfma<2><<<dim3(4*DD/128, ROWS/128),256,0,stream>>>(Hb, fc_w, (size_t)l*FC_S,
                                                                nullptr, BIG, ROWS, 4*DD, DD, FLAG);
        gemm_mfma<1><<<dim3(DD/128, ROWS/128),256,0,stream>>>(BIG, fcp_w, (size_t)l*FC_S,
                                                              X, nullptr, ROWS, DD, 4*DD, FLAG);
    }
    ln_kernel<<<ROWS,64,0,stream>>>(X, lnf_w, 0, Hb, FLAG);
    gemm_nt3<<<dim3((VV+63)/64, ROWS/64),256,0,stream>>>(Hb, wte, 0, out, ROWS, VV, DD, FLAG);
    loss_kernel<<<ROWS,64,0,stream>>>(out, targets, ACC);
    fin_loss<<<1,1,0,stream>>>(ACC, out + (size_t)ROWS*VV);
}

// Round 9
// 2156.150 us; speedup vs baseline: 1.4063x; 1.4063x over previous
//
#include <hip/hip_runtime.h>
#include <hip/hip_bf16.h>
#include <math.h>

#define BB 4
#define TT 2048
#define VV 99
#define DD 512
#define HH 8
#define LL 6
#define DHH 64
#define OFFS 28
#define ROWS (BB*TT)   // 8192

typedef __hip_bfloat16 bf16;
typedef __attribute__((ext_vector_type(8))) short bf16x8;
typedef __attribute__((ext_vector_type(4))) float f32x4;

__device__ __forceinline__ float b2f(bf16 x){ return __bfloat162float(x); }

// mode-dispatched weight read from a raw base + element offset (mode1 = bf16 inputs)
__device__ __forceinline__ float wget(const void* w, int mode, size_t i){
    return mode ? b2f(((const bf16*)w)[i]) : ((const float*)w)[i];
}

// ---------------- init ----------------
__global__ void init_kernel(const unsigned int* __restrict__ ln1_bits, float* __restrict__ acc,
                            int* __restrict__ flag){
    acc[0] = 0.f; acc[1] = 0.f;
    flag[0] = (ln1_bits[0] == 0x3F800000u) ? 0 : 1;
}

// ---------------- weight convert: any-dtype -> bf16, 8 elems/thread ----------------
__global__ __launch_bounds__(256) void wconv_kernel(const void* __restrict__ src,
                                                    bf16* __restrict__ dst, int n,
                                                    const int* __restrict__ flag){
    int mode = flag[0];
    size_t i0 = ((size_t)blockIdx.x*256 + threadIdx.x)*8;
    if (i0 >= (size_t)n) return;
    if (mode == 0){
        const float4* sp = (const float4*)((const float*)src + i0);
        float4 a = sp[0], b = sp[1];
        float f[8] = {a.x,a.y,a.z,a.w, b.x,b.y,b.z,b.w};
        union { short s[8]; uint4 u; } cv;
        #pragma unroll
        for (int k=0;k<8;++k) cv.s[k] = __bfloat16_as_short(__float2bfloat16(f[k]));
        *(uint4*)(dst + i0) = cv.u;
    } else {
        *(uint4*)(dst + i0) = *(const uint4*)((const bf16*)src + i0);
    }
}

// ---------------- embedding ----------------
__global__ void embed_kernel(const int* __restrict__ idx, const void* __restrict__ wte,
                             const void* __restrict__ wpe, float* __restrict__ x,
                             const int* __restrict__ flag){
    int mode = flag[0];
    int row = blockIdx.x;
    int t = row % TT;
    int tok = idx[row];
    int i = threadIdx.x;
    #pragma unroll
    for (int j = 0; j < 2; ++j){
        int d = i + j*256;
        x[(size_t)row*DD + d] = wget(wte, mode, (size_t)tok*DD + d)
                              + wget(wpe, mode, (size_t)t*DD + d);
    }
}

// ---------------- layernorm: fp32 in, bf16 out ----------------
__global__ void ln_kernel(const float* __restrict__ x, const void* __restrict__ w,
                          size_t woff, bf16* __restrict__ out, const int* __restrict__ flag){
    int mode = flag[0];
    int row = blockIdx.x;
    int lane = threadIdx.x; // 64
    const float* xr = x + (size_t)row*DD;
    float v[8];
    float s = 0.f;
    #pragma unroll
    for (int j=0;j<8;++j){ v[j] = xr[lane + j*64]; s += v[j]; }
    #pragma unroll
    for (int o=32;o;o>>=1) s += __shfl_xor(s,o);
    float mean = s * (1.0f/DD);
    float vs = 0.f;
    #pragma unroll
    for (int j=0;j<8;++j){ float d = v[j]-mean; vs += d*d; }
    #pragma unroll
    for (int o=32;o;o>>=1) vs += __shfl_xor(vs,o);
    float rstd = rsqrtf(vs*(1.0f/DD) + 1e-5f);
    #pragma unroll
    for (int j=0;j<8;++j){
        int d = lane + j*64;
        out[(size_t)row*DD + d] = __float2bfloat16((v[j]-mean)*rstd*wget(w,mode,woff+d));
    }
}

// ---------------- MFMA GEMM: C[M,N] = A[M,K] @ W[N,K]^T (A,W both bf16) ----------------
// 128x128 tile, BK=32, 4 waves x (4x4) 16x16x32 bf16 MFMA frags.
// EPI: 0 = bf16 store Cb, 1 = fp32 += C (residual), 2 = gelu -> bf16 Cb
template<int EPI>
__global__ __launch_bounds__(256) void gemm_mfma(const bf16* __restrict__ A,
        const bf16* __restrict__ W, float* __restrict__ C, bf16* __restrict__ Cb,
        int M, int N, int K){
    __shared__ short As[128*32];
    __shared__ short Ws[128*32];
    int tid = threadIdx.x;
    int m0 = blockIdx.y * 128;
    int n0 = blockIdx.x * 128;
    int lane = tid & 63, wave = tid >> 6;
    int wm = (wave & 1) * 64, wn = (wave >> 1) * 64;
    int quad = lane >> 4, l16 = lane & 15;

    f32x4 acc[4][4] = {};

    int ra = tid >> 1;
    int ha = (tid & 1) * 16;

    for (int k0 = 0; k0 < K; k0 += 32){
        __syncthreads();
        {
            const uint4* gp = (const uint4*)(A + (size_t)(m0+ra)*K + k0 + ha);
            uint4 v0 = gp[0], v1 = gp[1];
            *(uint4*)&As[ra*32 + ha]     = v0;
            *(uint4*)&As[ra*32 + ha + 8] = v1;
        }
        {
            const uint4* wp = (const uint4*)(W + (size_t)(n0+ra)*K + k0 + ha);
            uint4 v0 = wp[0], v1 = wp[1];
            *(uint4*)&Ws[ra*32 + ha]     = v0;
            *(uint4*)&Ws[ra*32 + ha + 8] = v1;
        }
        __syncthreads();

        bf16x8 af[4], bf[4];
        #pragma unroll
        for (int mi=0;mi<4;++mi)
            af[mi] = *(const bf16x8*)&As[(wm + mi*16 + l16)*32 + quad*8];
        #pragma unroll
        for (int ni=0;ni<4;++ni)
            bf[ni] = *(const bf16x8*)&Ws[(wn + ni*16 + l16)*32 + quad*8];
        #pragma unroll
        for (int mi=0;mi<4;++mi)
            #pragma unroll
            for (int ni=0;ni<4;++ni)
                acc[mi][ni] = __builtin_amdgcn_mfma_f32_16x16x32_bf16(af[mi], bf[ni], acc[mi][ni], 0, 0, 0);
    }

    #pragma unroll
    for (int mi=0;mi<4;++mi){
        #pragma unroll
        for (int ni=0;ni<4;++ni){
            int mg = m0 + wm + mi*16 + quad*4;
            int ng = n0 + wn + ni*16 + l16;
            #pragma unroll
            for (int reg=0;reg<4;++reg){
                float val = acc[mi][ni][reg];
                size_t off = (size_t)(mg+reg)*N + ng;
                if (EPI==0){
                    Cb[off] = __float2bfloat16(val);
                } else if (EPI==1){
                    C[off] += val;
                } else {
                    float xx = val;
                    float u = 0.7978845608028654f*(xx + 0.044715f*xx*xx*xx);
                    Cb[off] = __float2bfloat16(0.5f*xx*(1.0f+tanhf(u)));
                }
            }
        }
    }
}

// ---------------- VALU GEMM (kept for logits: N=99), fp32 store ----------------
__global__ __launch_bounds__(256) void gemm_nt3(const bf16* __restrict__ A,
        const void* __restrict__ W, size_t woff, float* __restrict__ C,
        int M, int N, int K, const int* __restrict__ flag){
    int mode = flag[0];
    __shared__ float As[16][64];
    __shared__ float Wt[16][64];
    int m0 = blockIdx.y * 64;
    int n0 = blockIdx.x * 64;
    int t = threadIdx.x;
    int tx = t & 15, ty = t >> 4;
    float acc[4][4] = {};
    int am = t >> 2;
    int ak = (t & 3) * 4;

    for (int k0 = 0; k0 < K; k0 += 16){
        {
            const __hip_bfloat162* ap = (const __hip_bfloat162*)(A + (size_t)(m0+am)*K + k0 + ak);
            __hip_bfloat162 p0 = ap[0], p1 = ap[1];
            float2 f0 = __bfloat1622float2(p0), f1 = __bfloat1622float2(p1);
            As[ak+0][am]=f0.x; As[ak+1][am]=f0.y; As[ak+2][am]=f1.x; As[ak+3][am]=f1.y;
        }
        int wn = n0 + am;
        if (wn < N){
            size_t off = woff + (size_t)wn*K + k0 + ak;
            if (mode == 0){
                float4 wv = *(const float4*)((const float*)W + off);
                Wt[ak+0][am]=wv.x; Wt[ak+1][am]=wv.y; Wt[ak+2][am]=wv.z; Wt[ak+3][am]=wv.w;
            } else {
                const __hip_bfloat162* wp = (const __hip_bfloat162*)((const bf16*)W + off);
                __hip_bfloat162 p0 = wp[0], p1 = wp[1];
                float2 f0 = __bfloat1622float2(p0), f1 = __bfloat1622float2(p1);
                Wt[ak+0][am]=f0.x; Wt[ak+1][am]=f0.y; Wt[ak+2][am]=f1.x; Wt[ak+3][am]=f1.y;
            }
        } else {
            Wt[ak+0][am]=0.f; Wt[ak+1][am]=0.f; Wt[ak+2][am]=0.f; Wt[ak+3][am]=0.f;
        }
        __syncthreads();
        #pragma unroll
        for (int kk=0;kk<16;++kk){
            float a[4], b[4];
            #pragma unroll
            for (int i=0;i<4;++i) a[i]=As[kk][ty*4+i];
            #pragma unroll
            for (int j=0;j<4;++j) b[j]=Wt[kk][tx*4+j];
            #pragma unroll
            for (int i=0;i<4;++i)
                #pragma unroll
                for (int j=0;j<4;++j)
                    acc[i][j] += a[i]*b[j];
        }
        __syncthreads();
    }

    #pragma unroll
    for (int i=0;i<4;++i){
        int m = m0 + ty*4 + i;
        #pragma unroll
        for (int j=0;j<4;++j){
            int n = n0 + tx*4 + j;
            if (n >= N) continue;
            C[(size_t)m*N+n] = acc[i][j];
        }
    }
}

// ---------------- attention v5: MFMA flash, cooperative staging, V^T in LDS ----------------
// One wg per (b,h,qtile64); 4 waves each own 16 q rows.
// Q A-frags direct from global; K staged row-major; V staged TRANSPOSED (Vt[d][j]) so
// PV B-frags are 16B contiguous; P via per-wave LDS scratch.
#define AST 72
__global__ __launch_bounds__(256) void attn_mfma5(const bf16* __restrict__ qkv,
                                                  bf16* __restrict__ y){
    __shared__ short Ks[64*AST];
    __shared__ short Vt[64*AST];
    __shared__ short Ps[4*16*AST];

    int tid = threadIdx.x;
    int lane = tid & 63, wave = tid >> 6;
    int quad = lane >> 4, l16 = lane & 15;

    int bi = blockIdx.x;
    int qt = 31 - (bi & 31);       // big tiles first
    int bh = bi >> 5;
    int h = bh & 7;
    int b = bh >> 3;
    int q0 = qt * 64;
    size_t base = (size_t)b * TT * 1536;

    int r  = tid >> 2;             // 0..63 staging row
    int dc = (tid & 3) << 4;       // 0,16,32,48

    // Q A-frags direct from global (row-major, 16B contiguous)
    const bf16* qrow = qkv + base + (size_t)(q0 + wave*16 + l16)*1536 + h*64;
    bf16x8 aq0 = *(const bf16x8*)(qrow + quad*8);
    bf16x8 aq1 = *(const bf16x8*)(qrow + 32 + quad*8);

    f32x4 O[4] = {};
    float mr[4] = {-1e30f,-1e30f,-1e30f,-1e30f};
    float lr[4] = {0.f,0.f,0.f,0.f};

    short* pw = &Ps[wave*16*AST];
    int jbmax = qt + 1; if (jbmax > 31) jbmax = 31;

    for (int jb = 0; jb <= jbmax; ++jb){
        int j0 = jb * 64;
        __syncthreads();
        // stage K row-major
        {
            const uint4* gp = (const uint4*)(qkv + base + (size_t)(j0 + r)*1536 + DD + h*64 + dc);
            uint4 v0 = gp[0], v1 = gp[1];
            *(uint4*)&Ks[r*AST + dc]     = v0;
            *(uint4*)&Ks[r*AST + dc + 8] = v1;
        }
        // stage V transposed: Vt[d][j]
        {
            const uint4* gp = (const uint4*)(qkv + base + (size_t)(j0 + r)*1536 + 2*DD + h*64 + dc);
            uint4 v0 = gp[0], v1 = gp[1];
            short tmp[16];
            *(uint4*)&tmp[0] = v0; *(uint4*)&tmp[8] = v1;
            #pragma unroll
            for (int k=0;k<16;++k) Vt[(dc+k)*AST + r] = tmp[k];
        }
        __syncthreads();

        // S = Q K^T (wave's 16 q x 64 j)
        f32x4 s[4];
        #pragma unroll
        for (int ni=0; ni<4; ++ni){
            bf16x8 bk0 = *(const bf16x8*)&Ks[(ni*16 + l16)*AST + quad*8];
            bf16x8 bk1 = *(const bf16x8*)&Ks[(ni*16 + l16)*AST + 32 + quad*8];
            f32x4 z = {};
            z = __builtin_amdgcn_mfma_f32_16x16x32_bf16(aq0, bk0, z, 0, 0, 0);
            z = __builtin_amdgcn_mfma_f32_16x16x32_bf16(aq1, bk1, z, 0, 0, 0);
            s[ni] = z;
        }

        // scale + mask (C-layout: row=quad*4+reg, col=ni*16+l16)
        float sc[4][4];
        bool bd = (j0 + 63 > q0 + OFFS);
        #pragma unroll
        for (int ni=0; ni<4; ++ni){
            #pragma unroll
            for (int reg=0; reg<4; ++reg){
                float v = s[ni][reg] * 0.125f;
                if (bd){
                    int qg = q0 + wave*16 + quad*4 + reg;
                    int jg = j0 + ni*16 + l16;
                    if (jg > qg + OFFS) v = -1e30f;
                }
                sc[ni][reg] = v;
            }
        }
        // online softmax
        float bm[4], alpha[4], rs[4];
        #pragma unroll
        for (int reg=0; reg<4; ++reg)
            bm[reg] = fmaxf(fmaxf(sc[0][reg], sc[1][reg]), fmaxf(sc[2][reg], sc[3][reg]));
        #pragma unroll
        for (int o=1;o<16;o<<=1){
            #pragma unroll
            for (int reg=0; reg<4; ++reg) bm[reg] = fmaxf(bm[reg], __shfl_xor(bm[reg], o));
        }
        #pragma unroll
        for (int reg=0; reg<4; ++reg){
            float nm = fmaxf(mr[reg], bm[reg]);
            alpha[reg] = __expf(mr[reg] - nm);
            mr[reg] = nm;
            rs[reg] = 0.f;
            #pragma unroll
            for (int ni=0; ni<4; ++ni){
                sc[ni][reg] = __expf(sc[ni][reg] - nm);
                rs[reg] += sc[ni][reg];
            }
        }
        #pragma unroll
        for (int o=1;o<16;o<<=1){
            #pragma unroll
            for (int reg=0; reg<4; ++reg) rs[reg] += __shfl_xor(rs[reg], o);
        }
        #pragma unroll
        for (int reg=0; reg<4; ++reg){
            lr[reg] = lr[reg]*alpha[reg] + rs[reg];
            #pragma unroll
            for (int dt=0; dt<4; ++dt) O[dt][reg] *= alpha[reg];
        }

        // P: C-layout -> A-layout via per-wave LDS
        #pragma unroll
        for (int ni=0; ni<4; ++ni)
            #pragma unroll
            for (int reg=0; reg<4; ++reg)
                pw[(quad*4+reg)*AST + ni*16 + l16] =
                    __bfloat16_as_short(__float2bfloat16(sc[ni][reg]));
        bf16x8 ap0 = *(const bf16x8*)&pw[l16*AST + quad*8];
        bf16x8 ap1 = *(const bf16x8*)&pw[l16*AST + 32 + quad*8];

        // O += P V : B-frags = Vt rows (16B contiguous)
        #pragma unroll
        for (int dt=0; dt<4; ++dt){
            bf16x8 bv0 = *(const bf16x8*)&Vt[(dt*16 + l16)*AST + quad*8];
            bf16x8 bv1 = *(const bf16x8*)&Vt[(dt*16 + l16)*AST + 32 + quad*8];
            O[dt] = __builtin_amdgcn_mfma_f32_16x16x32_bf16(ap0, bv0, O[dt], 0, 0, 0);
            O[dt] = __builtin_amdgcn_mfma_f32_16x16x32_bf16(ap1, bv1, O[dt], 0, 0, 0);
        }
    }

    // epilogue
    float inv[4];
    #pragma unroll
    for (int reg=0; reg<4; ++reg) inv[reg] = 1.0f / lr[reg];
    #pragma unroll
    for (int dt=0; dt<4; ++dt){
        #pragma unroll
        for (int reg=0; reg<4; ++reg){
            int qg = q0 + wave*16 + quad*4 + reg;
            y[((size_t)b*TT + qg)*DD + h*64 + dt*16 + l16] =
                __float2bfloat16(O[dt][reg] * inv[reg]);
        }
    }
}

// ---------------- loss (fp32 logits) ----------------
__global__ void loss_kernel(const float* __restrict__ logits, const int* __restrict__ targets,
                            float* __restrict__ acc){
    int row = blockIdx.x;
    int lane = threadIdx.x;
    int yt = targets[row];
    const float* lp = logits + (size_t)row*VV;
    float e0 = (lane < VV)    ? lp[lane]    : -1e30f;
    float e1 = (lane+64 < VV) ? lp[lane+64] : -1e30f;
    float mx = fmaxf(e0,e1);
    #pragma unroll
    for (int o=32;o;o>>=1) mx = fmaxf(mx, __shfl_xor(mx,o));
    float se = 0.f;
    if (lane < VV)    se += __expf(e0-mx);
    if (lane+64 < VV) se += __expf(e1-mx);
    #pragma unroll
    for (int o=32;o;o>>=1) se += __shfl_xor(se,o);
    if (lane == 0 && yt >= 0){
        float wi = (yt>=78 && yt<96) ? 1.0f : (yt==96 ? 0.1f : 0.0f);
        if (wi > 0.f){
            float ly = lp[yt];
            float nll = -(ly - mx - logf(se));
            atomicAdd(&acc[0], wi*nll);
            atomicAdd(&acc[1], wi);
        }
    }
}

__global__ void fin_loss(const float* __restrict__ acc, float* __restrict__ out){
    out[0] = acc[0]/acc[1];
}

// ---------------- launch ----------------
extern "C" void kernel_launch(void* const* d_in, const int* in_sizes, int n_in,
                              void* d_out, int out_size, void* d_ws, size_t ws_size,
                              hipStream_t stream){
    const int*  idx     = (const int*) d_in[0];
    const int*  targets = (const int*) d_in[1];
    const void* wte     = d_in[2];
    const void* wpe     = d_in[3];
    const void* ln1_w   = d_in[4];
    const void* attn_w  = d_in[5];
    const void* proj_w  = d_in[6];
    const void* ln2_w   = d_in[7];
    const void* fc_w    = d_in[8];
    const void* fcp_w   = d_in[9];
    const void* lnf_w   = d_in[10];
    float* out = (float*)d_out;   // fp32: logits [8192,99] then loss [1]

    // workspace layout (float-slot offsets), total ~92 MiB
    float* ws   = (float*)d_ws;
    float* ACC  = ws;
    int*   FLAG = (int*)(ws + 4);
    bf16*  Hb   = (bf16*)(ws + 16);                      // [8192,512]  bf16 (8MB)
    float* X    = ws + 2097168;                          // [8192,512]  fp32 (16MB)
    bf16*  BIG  = (bf16*)(ws + 6291472);                 // [8192,2048] bf16 (32MB)
    bf16*  WB   = (bf16*)(ws + 14680080);                // converted weights, 18.87M bf16 (37.7MB)

    const int ATT_S = 3*DD*DD;        // 786432
    const int PRJ_S = DD*DD;          // 262144
    const int FC_S  = 4*DD*DD;        // 1048576
    bf16* WB_att = WB;
    bf16* WB_prj = WB + (size_t)6*ATT_S;
    bf16* WB_fc  = WB_prj + (size_t)6*PRJ_S;
    bf16* WB_fcp = WB_fc  + (size_t)6*FC_S;

    init_kernel<<<1,1,0,stream>>>((const unsigned int*)ln1_w, ACC, FLAG);
    wconv_kernel<<<(6*ATT_S)/2048,256,0,stream>>>(attn_w, WB_att, 6*ATT_S, FLAG);
    wconv_kernel<<<(6*PRJ_S)/2048,256,0,stream>>>(proj_w, WB_prj, 6*PRJ_S, FLAG);
    wconv_kernel<<<(6*FC_S)/2048,256,0,stream>>>(fc_w,  WB_fc,  6*FC_S, FLAG);
    wconv_kernel<<<(6*FC_S)/2048,256,0,stream>>>(fcp_w, WB_fcp, 6*FC_S, FLAG);
    embed_kernel<<<ROWS,256,0,stream>>>(idx, wte, wpe, X, FLAG);
    for (int l=0; l<LL; ++l){
        ln_kernel<<<ROWS,64,0,stream>>>(X, ln1_w, (size_t)l*DD, Hb, FLAG);
        gemm_mfma<0><<<dim3(3*DD/128, ROWS/128),256,0,stream>>>(Hb, WB_att + (size_t)l*ATT_S,
                                                                nullptr, BIG, ROWS, 3*DD, DD);
        attn_mfma5<<<dim3(BB*HH*32),256,0,stream>>>(BIG, Hb);
        gemm_mfma<1><<<dim3(DD/128, ROWS/128),256,0,stream>>>(Hb, WB_prj + (size_t)l*PRJ_S,
                                                              X, nullptr, ROWS, DD, DD);
        ln_kernel<<<ROWS,64,0,stream>>>(X, ln2_w, (size_t)l*DD, Hb, FLAG);
        gemm_mfma<2><<<dim3(4*DD/128, ROWS/128),256,0,stream>>>(Hb, WB_fc + (size_t)l*FC_S,
                                                                nullptr, BIG, ROWS, 4*DD, DD);
        gemm_mfma<1><<<dim3(DD/128, ROWS/128),256,0,stream>>>(BIG, WB_fcp + (size_t)l*FC_S,
                                                              X, nullptr, ROWS, DD, 4*DD);
    }
    ln_kernel<<<ROWS,64,0,stream>>>(X, lnf_w, 0, Hb, FLAG);
    gemm_nt3<<<dim3((VV+63)/64, ROWS/64),256,0,stream>>>(Hb, wte, 0, out, ROWS, VV, DD, FLAG);
    loss_kernel<<<ROWS,64,0,stream>>>(out, targets, ACC);
    fin_loss<<<1,1,0,stream>>>(ACC, out + (size_t)ROWS*VV);
}

// Round 10
// 2009.980 us; speedup vs baseline: 1.5086x; 1.0727x over previous
//
#include <hip/hip_runtime.h>
#include <hip/hip_bf16.h>
#include <math.h>

#define BB 4
#define TT 2048
#define VV 99
#define DD 512
#define HH 8
#define LL 6
#define DHH 64
#define OFFS 28
#define ROWS (BB*TT)   // 8192

typedef __hip_bfloat16 bf16;
typedef __attribute__((ext_vector_type(8))) short bf16x8;
typedef __attribute__((ext_vector_type(4))) float f32x4;

__device__ __forceinline__ float b2f(bf16 x){ return __bfloat162float(x); }

// async 16B/lane global->LDS. LDS dest = wave-uniform base + lane*16 (m97 pattern).
__device__ __forceinline__ void async_copy16(const void* g, void* l){
    __builtin_amdgcn_global_load_lds(
        (const __attribute__((address_space(1))) unsigned int*)g,
        (__attribute__((address_space(3))) unsigned int*)l, 16, 0, 0);
}

// mode-dispatched weight read from a raw base + element offset (mode1 = bf16 inputs)
__device__ __forceinline__ float wget(const void* w, int mode, size_t i){
    return mode ? b2f(((const bf16*)w)[i]) : ((const float*)w)[i];
}

// ---------------- init ----------------
__global__ void init_kernel(const unsigned int* __restrict__ ln1_bits, float* __restrict__ acc,
                            int* __restrict__ flag){
    acc[0] = 0.f; acc[1] = 0.f;
    flag[0] = (ln1_bits[0] == 0x3F800000u) ? 0 : 1;
}

// ---------------- weight convert: any-dtype -> bf16, 8 elems/thread ----------------
__global__ __launch_bounds__(256) void wconv_kernel(const void* __restrict__ src,
                                                    bf16* __restrict__ dst, int n,
                                                    const int* __restrict__ flag){
    int mode = flag[0];
    size_t i0 = ((size_t)blockIdx.x*256 + threadIdx.x)*8;
    if (i0 >= (size_t)n) return;
    if (mode == 0){
        const float4* sp = (const float4*)((const float*)src + i0);
        float4 a = sp[0], b = sp[1];
        float f[8] = {a.x,a.y,a.z,a.w, b.x,b.y,b.z,b.w};
        union { short s[8]; uint4 u; } cv;
        #pragma unroll
        for (int k=0;k<8;++k) cv.s[k] = __bfloat16_as_short(__float2bfloat16(f[k]));
        *(uint4*)(dst + i0) = cv.u;
    } else {
        *(uint4*)(dst + i0) = *(const uint4*)((const bf16*)src + i0);
    }
}

// ---------------- embedding ----------------
__global__ void embed_kernel(const int* __restrict__ idx, const void* __restrict__ wte,
                             const void* __restrict__ wpe, float* __restrict__ x,
                             const int* __restrict__ flag){
    int mode = flag[0];
    int row = blockIdx.x;
    int t = row % TT;
    int tok = idx[row];
    int i = threadIdx.x;
    #pragma unroll
    for (int j = 0; j < 2; ++j){
        int d = i + j*256;
        x[(size_t)row*DD + d] = wget(wte, mode, (size_t)tok*DD + d)
                              + wget(wpe, mode, (size_t)t*DD + d);
    }
}

// ---------------- layernorm: fp32 in, bf16 out ----------------
__global__ void ln_kernel(const float* __restrict__ x, const void* __restrict__ w,
                          size_t woff, bf16* __restrict__ out, const int* __restrict__ flag){
    int mode = flag[0];
    int row = blockIdx.x;
    int lane = threadIdx.x; // 64
    const float* xr = x + (size_t)row*DD;
    float v[8];
    float s = 0.f;
    #pragma unroll
    for (int j=0;j<8;++j){ v[j] = xr[lane + j*64]; s += v[j]; }
    #pragma unroll
    for (int o=32;o;o>>=1) s += __shfl_xor(s,o);
    float mean = s * (1.0f/DD);
    float vs = 0.f;
    #pragma unroll
    for (int j=0;j<8;++j){ float d = v[j]-mean; vs += d*d; }
    #pragma unroll
    for (int o=32;o;o>>=1) vs += __shfl_xor(vs,o);
    float rstd = rsqrtf(vs*(1.0f/DD) + 1e-5f);
    #pragma unroll
    for (int j=0;j<8;++j){
        int d = lane + j*64;
        out[(size_t)row*DD + d] = __float2bfloat16((v[j]-mean)*rstd*wget(w,mode,woff+d));
    }
}

// ---------------- MFMA GEMM: C[M,N] = A[M,K] @ W[N,K]^T (A,W both bf16) ----------------
// 128x128 tile, BK=32, global_load_lds width-16 staging (m97 pattern).
// EPI: 0 = bf16 store Cb, 1 = fp32 += C (residual), 2 = gelu -> bf16 Cb
template<int EPI>
__global__ __launch_bounds__(256) void gemm_mfma(const bf16* __restrict__ A,
        const bf16* __restrict__ W, float* __restrict__ C, bf16* __restrict__ Cb,
        int M, int N, int K){
    __shared__ short As[128*32];
    __shared__ short Ws[128*32];
    int tid = threadIdx.x;
    int m0 = blockIdx.y * 128;
    int n0 = blockIdx.x * 128;
    int lane = tid & 63, wave = tid >> 6;
    int wm = (wave & 1) * 64, wn = (wave >> 1) * 64;
    int quad = lane >> 4, l16 = lane & 15;

    f32x4 acc[4][4] = {};

    // staging: lane l of wave w covers row w*16 + l/4 (+0 / +64), col (l%4)*8
    int srow = wave*16 + (lane >> 2);
    int scol = (lane & 3) * 8;
    const bf16* ga = A + (size_t)(m0 + srow)*K + scol;
    const bf16* gw = W + (size_t)(n0 + srow)*K + scol;
    short* laA0 = &As[(wave*16)*32];
    short* laA1 = &As[(64 + wave*16)*32];
    short* laW0 = &Ws[(wave*16)*32];
    short* laW1 = &Ws[(64 + wave*16)*32];

    for (int k0 = 0; k0 < K; k0 += 32){
        __syncthreads();
        async_copy16(ga + k0,                 laA0);
        async_copy16(ga + (size_t)64*K + k0,  laA1);
        async_copy16(gw + k0,                 laW0);
        async_copy16(gw + (size_t)64*K + k0,  laW1);
        __syncthreads();

        bf16x8 af[4], bf[4];
        #pragma unroll
        for (int mi=0;mi<4;++mi)
            af[mi] = *(const bf16x8*)&As[(wm + mi*16 + l16)*32 + quad*8];
        #pragma unroll
        for (int ni=0;ni<4;++ni)
            bf[ni] = *(const bf16x8*)&Ws[(wn + ni*16 + l16)*32 + quad*8];
        #pragma unroll
        for (int mi=0;mi<4;++mi)
            #pragma unroll
            for (int ni=0;ni<4;++ni)
                acc[mi][ni] = __builtin_amdgcn_mfma_f32_16x16x32_bf16(af[mi], bf[ni], acc[mi][ni], 0, 0, 0);
    }

    #pragma unroll
    for (int mi=0;mi<4;++mi){
        #pragma unroll
        for (int ni=0;ni<4;++ni){
            int mg = m0 + wm + mi*16 + quad*4;
            int ng = n0 + wn + ni*16 + l16;
            #pragma unroll
            for (int reg=0;reg<4;++reg){
                float val = acc[mi][ni][reg];
                size_t off = (size_t)(mg+reg)*N + ng;
                if (EPI==0){
                    Cb[off] = __float2bfloat16(val);
                } else if (EPI==1){
                    C[off] += val;
                } else {
                    float xx = val;
                    float u = 0.7978845608028654f*(xx + 0.044715f*xx*xx*xx);
                    Cb[off] = __float2bfloat16(0.5f*xx*(1.0f+tanhf(u)));
                }
            }
        }
    }
}

// ---------------- VALU GEMM (kept for logits: N=99), fp32 store ----------------
__global__ __launch_bounds__(256) void gemm_nt3(const bf16* __restrict__ A,
        const void* __restrict__ W, size_t woff, float* __restrict__ C,
        int M, int N, int K, const int* __restrict__ flag){
    int mode = flag[0];
    __shared__ float As[16][64];
    __shared__ float Wt[16][64];
    int m0 = blockIdx.y * 64;
    int n0 = blockIdx.x * 64;
    int t = threadIdx.x;
    int tx = t & 15, ty = t >> 4;
    float acc[4][4] = {};
    int am = t >> 2;
    int ak = (t & 3) * 4;

    for (int k0 = 0; k0 < K; k0 += 16){
        {
            const __hip_bfloat162* ap = (const __hip_bfloat162*)(A + (size_t)(m0+am)*K + k0 + ak);
            __hip_bfloat162 p0 = ap[0], p1 = ap[1];
            float2 f0 = __bfloat1622float2(p0), f1 = __bfloat1622float2(p1);
            As[ak+0][am]=f0.x; As[ak+1][am]=f0.y; As[ak+2][am]=f1.x; As[ak+3][am]=f1.y;
        }
        int wn = n0 + am;
        if (wn < N){
            size_t off = woff + (size_t)wn*K + k0 + ak;
            if (mode == 0){
                float4 wv = *(const float4*)((const float*)W + off);
                Wt[ak+0][am]=wv.x; Wt[ak+1][am]=wv.y; Wt[ak+2][am]=wv.z; Wt[ak+3][am]=wv.w;
            } else {
                const __hip_bfloat162* wp = (const __hip_bfloat162*)((const bf16*)W + off);
                __hip_bfloat162 p0 = wp[0], p1 = wp[1];
                float2 f0 = __bfloat1622float2(p0), f1 = __bfloat1622float2(p1);
                Wt[ak+0][am]=f0.x; Wt[ak+1][am]=f0.y; Wt[ak+2][am]=f1.x; Wt[ak+3][am]=f1.y;
            }
        } else {
            Wt[ak+0][am]=0.f; Wt[ak+1][am]=0.f; Wt[ak+2][am]=0.f; Wt[ak+3][am]=0.f;
        }
        __syncthreads();
        #pragma unroll
        for (int kk=0;kk<16;++kk){
            float a[4], b[4];
            #pragma unroll
            for (int i=0;i<4;++i) a[i]=As[kk][ty*4+i];
            #pragma unroll
            for (int j=0;j<4;++j) b[j]=Wt[kk][tx*4+j];
            #pragma unroll
            for (int i=0;i<4;++i)
                #pragma unroll
                for (int j=0;j<4;++j)
                    acc[i][j] += a[i]*b[j];
        }
        __syncthreads();
    }

    #pragma unroll
    for (int i=0;i<4;++i){
        int m = m0 + ty*4 + i;
        #pragma unroll
        for (int j=0;j<4;++j){
            int n = n0 + tx*4 + j;
            if (n >= N) continue;
            C[(size_t)m*N+n] = acc[i][j];
        }
    }
}

// ---------------- attention v6: MFMA flash, swizzled V^T staging ----------------
// One wg per (b,h,qtile64); 4 waves each own 16 q rows.
// Vt element (d,j) stored at d*AST + (jblk ^ ((d>>3)&7))*8 + (j&7): writes spread
// over all 32 banks (2 lanes/bank = free), reads stay one aligned ds_read_b128.
#define AST 72
__global__ __launch_bounds__(256) void attn_mfma6(const bf16* __restrict__ qkv,
                                                  bf16* __restrict__ y){
    __shared__ short Ks[64*AST];
    __shared__ short Vt[64*AST];
    __shared__ short Ps[4*16*AST];

    int tid = threadIdx.x;
    int lane = tid & 63, wave = tid >> 6;
    int quad = lane >> 4, l16 = lane & 15;

    int bi = blockIdx.x;
    int qt = 31 - (bi & 31);       // big tiles first
    int bh = bi >> 5;
    int h = bh & 7;
    int b = bh >> 3;
    int q0 = qt * 64;
    size_t base = (size_t)b * TT * 1536;

    int r  = tid >> 2;             // 0..63 staging row
    int dc = (tid & 3) << 4;       // 0,16,32,48

    // Q A-frags direct from global (row-major, 16B contiguous)
    const bf16* qrow = qkv + base + (size_t)(q0 + wave*16 + l16)*1536 + h*64;
    bf16x8 aq0 = *(const bf16x8*)(qrow + quad*8);
    bf16x8 aq1 = *(const bf16x8*)(qrow + 32 + quad*8);

    f32x4 O[4] = {};
    float mr[4] = {-1e30f,-1e30f,-1e30f,-1e30f};
    float lr[4] = {0.f,0.f,0.f,0.f};

    short* pw = &Ps[wave*16*AST];
    int jbmax = qt + 1; if (jbmax > 31) jbmax = 31;

    for (int jb = 0; jb <= jbmax; ++jb){
        int j0 = jb * 64;
        __syncthreads();
        // stage K row-major
        {
            const uint4* gp = (const uint4*)(qkv + base + (size_t)(j0 + r)*1536 + DD + h*64 + dc);
            uint4 v0 = gp[0], v1 = gp[1];
            *(uint4*)&Ks[r*AST + dc]     = v0;
            *(uint4*)&Ks[r*AST + dc + 8] = v1;
        }
        // stage V transposed with j-block XOR swizzle
        {
            const uint4* gp = (const uint4*)(qkv + base + (size_t)(j0 + r)*1536 + 2*DD + h*64 + dc);
            uint4 v0 = gp[0], v1 = gp[1];
            short tmp[16];
            *(uint4*)&tmp[0] = v0; *(uint4*)&tmp[8] = v1;
            int jblk = r >> 3, jin = r & 7;
            #pragma unroll
            for (int k=0;k<16;++k){
                int d = dc + k;
                Vt[d*AST + ((jblk ^ ((d>>3)&7))<<3) + jin] = tmp[k];
            }
        }
        __syncthreads();

        // S = Q K^T (wave's 16 q x 64 j)
        f32x4 s[4];
        #pragma unroll
        for (int ni=0; ni<4; ++ni){
            bf16x8 bk0 = *(const bf16x8*)&Ks[(ni*16 + l16)*AST + quad*8];
            bf16x8 bk1 = *(const bf16x8*)&Ks[(ni*16 + l16)*AST + 32 + quad*8];
            f32x4 z = {};
            z = __builtin_amdgcn_mfma_f32_16x16x32_bf16(aq0, bk0, z, 0, 0, 0);
            z = __builtin_amdgcn_mfma_f32_16x16x32_bf16(aq1, bk1, z, 0, 0, 0);
            s[ni] = z;
        }

        // scale + mask (C-layout: row=quad*4+reg, col=ni*16+l16)
        float sc[4][4];
        bool bd = (j0 + 63 > q0 + OFFS);
        #pragma unroll
        for (int ni=0; ni<4; ++ni){
            #pragma unroll
            for (int reg=0; reg<4; ++reg){
                float v = s[ni][reg] * 0.125f;
                if (bd){
                    int qg = q0 + wave*16 + quad*4 + reg;
                    int jg = j0 + ni*16 + l16;
                    if (jg > qg + OFFS) v = -1e30f;
                }
                sc[ni][reg] = v;
            }
        }
        // online softmax
        float bm[4], alpha[4], rs[4];
        #pragma unroll
        for (int reg=0; reg<4; ++reg)
            bm[reg] = fmaxf(fmaxf(sc[0][reg], sc[1][reg]), fmaxf(sc[2][reg], sc[3][reg]));
        #pragma unroll
        for (int o=1;o<16;o<<=1){
            #pragma unroll
            for (int reg=0; reg<4; ++reg) bm[reg] = fmaxf(bm[reg], __shfl_xor(bm[reg], o));
        }
        #pragma unroll
        for (int reg=0; reg<4; ++reg){
            float nm = fmaxf(mr[reg], bm[reg]);
            alpha[reg] = __expf(mr[reg] - nm);
            mr[reg] = nm;
            rs[reg] = 0.f;
            #pragma unroll
            for (int ni=0; ni<4; ++ni){
                sc[ni][reg] = __expf(sc[ni][reg] - nm);
                rs[reg] += sc[ni][reg];
            }
        }
        #pragma unroll
        for (int o=1;o<16;o<<=1){
            #pragma unroll
            for (int reg=0; reg<4; ++reg) rs[reg] += __shfl_xor(rs[reg], o);
        }
        #pragma unroll
        for (int reg=0; reg<4; ++reg){
            lr[reg] = lr[reg]*alpha[reg] + rs[reg];
            #pragma unroll
            for (int dt=0; dt<4; ++dt) O[dt][reg] *= alpha[reg];
        }

        // P: C-layout -> A-layout via per-wave LDS
        #pragma unroll
        for (int ni=0; ni<4; ++ni)
            #pragma unroll
            for (int reg=0; reg<4; ++reg)
                pw[(quad*4+reg)*AST + ni*16 + l16] =
                    __bfloat16_as_short(__float2bfloat16(sc[ni][reg]));
        bf16x8 ap0 = *(const bf16x8*)&pw[l16*AST + quad*8];
        bf16x8 ap1 = *(const bf16x8*)&pw[l16*AST + 32 + quad*8];

        // O += P V : B-frags = swizzled Vt rows (one b128 each)
        #pragma unroll
        for (int dt=0; dt<4; ++dt){
            int d = dt*16 + l16;
            int sw = (d>>3) & 7;
            bf16x8 bv0 = *(const bf16x8*)&Vt[d*AST + ((quad     ^ sw)<<3)];
            bf16x8 bv1 = *(const bf16x8*)&Vt[d*AST + (((4+quad) ^ sw)<<3)];
            O[dt] = __builtin_amdgcn_mfma_f32_16x16x32_bf16(ap0, bv0, O[dt], 0, 0, 0);
            O[dt] = __builtin_amdgcn_mfma_f32_16x16x32_bf16(ap1, bv1, O[dt], 0, 0, 0);
        }
    }

    // epilogue
    float inv[4];
    #pragma unroll
    for (int reg=0; reg<4; ++reg) inv[reg] = 1.0f / lr[reg];
    #pragma unroll
    for (int dt=0; dt<4; ++dt){
        #pragma unroll
        for (int reg=0; reg<4; ++reg){
            int qg = q0 + wave*16 + quad*4 + reg;
            y[((size_t)b*TT + qg)*DD + h*64 + dt*16 + l16] =
                __float2bfloat16(O[dt][reg] * inv[reg]);
        }
    }
}

// ---------------- loss (fp32 logits) ----------------
__global__ void loss_kernel(const float* __restrict__ logits, const int* __restrict__ targets,
                            float* __restrict__ acc){
    int row = blockIdx.x;
    int lane = threadIdx.x;
    int yt = targets[row];
    const float* lp = logits + (size_t)row*VV;
    float e0 = (lane < VV)    ? lp[lane]    : -1e30f;
    float e1 = (lane+64 < VV) ? lp[lane+64] : -1e30f;
    float mx = fmaxf(e0,e1);
    #pragma unroll
    for (int o=32;o;o>>=1) mx = fmaxf(mx, __shfl_xor(mx,o));
    float se = 0.f;
    if (lane < VV)    se += __expf(e0-mx);
    if (lane+64 < VV) se += __expf(e1-mx);
    #pragma unroll
    for (int o=32;o;o>>=1) se += __shfl_xor(se,o);
    if (lane == 0 && yt >= 0){
        float wi = (yt>=78 && yt<96) ? 1.0f : (yt==96 ? 0.1f : 0.0f);
        if (wi > 0.f){
            float ly = lp[yt];
            float nll = -(ly - mx - logf(se));
            atomicAdd(&acc[0], wi*nll);
            atomicAdd(&acc[1], wi);
        }
    }
}

__global__ void fin_loss(const float* __restrict__ acc, float* __restrict__ out){
    out[0] = acc[0]/acc[1];
}

// ---------------- launch ----------------
extern "C" void kernel_launch(void* const* d_in, const int* in_sizes, int n_in,
                              void* d_out, int out_size, void* d_ws, size_t ws_size,
                              hipStream_t stream){
    const int*  idx     = (const int*) d_in[0];
    const int*  targets = (const int*) d_in[1];
    const void* wte     = d_in[2];
    const void* wpe     = d_in[3];
    const void* ln1_w   = d_in[4];
    const void* attn_w  = d_in[5];
    const void* proj_w  = d_in[6];
    const void* ln2_w   = d_in[7];
    const void* fc_w    = d_in[8];
    const void* fcp_w   = d_in[9];
    const void* lnf_w   = d_in[10];
    float* out = (float*)d_out;   // fp32: logits [8192,99] then loss [1]

    // workspace layout (float-slot offsets), total ~92 MiB
    float* ws   = (float*)d_ws;
    float* ACC  = ws;
    int*   FLAG = (int*)(ws + 4);
    bf16*  Hb   = (bf16*)(ws + 16);                      // [8192,512]  bf16 (8MB)
    float* X    = ws + 2097168;                          // [8192,512]  fp32 (16MB)
    bf16*  BIG  = (bf16*)(ws + 6291472);                 // [8192,2048] bf16 (32MB)
    bf16*  WB   = (bf16*)(ws + 14680080);                // converted weights (37.7MB)

    const int ATT_S = 3*DD*DD;        // 786432
    const int PRJ_S = DD*DD;          // 262144
    const int FC_S  = 4*DD*DD;        // 1048576
    bf16* WB_att = WB;
    bf16* WB_prj = WB + (size_t)6*ATT_S;
    bf16* WB_fc  = WB_prj + (size_t)6*PRJ_S;
    bf16* WB_fcp = WB_fc  + (size_t)6*FC_S;

    init_kernel<<<1,1,0,stream>>>((const unsigned int*)ln1_w, ACC, FLAG);
    wconv_kernel<<<(6*ATT_S)/2048,256,0,stream>>>(attn_w, WB_att, 6*ATT_S, FLAG);
    wconv_kernel<<<(6*PRJ_S)/2048,256,0,stream>>>(proj_w, WB_prj, 6*PRJ_S, FLAG);
    wconv_kernel<<<(6*FC_S)/2048,256,0,stream>>>(fc_w,  WB_fc,  6*FC_S, FLAG);
    wconv_kernel<<<(6*FC_S)/2048,256,0,stream>>>(fcp_w, WB_fcp, 6*FC_S, FLAG);
    embed_kernel<<<ROWS,256,0,stream>>>(idx, wte, wpe, X, FLAG);
    for (int l=0; l<LL; ++l){
        ln_kernel<<<ROWS,64,0,stream>>>(X, ln1_w, (size_t)l*DD, Hb, FLAG);
        gemm_mfma<0><<<dim3(3*DD/128, ROWS/128),256,0,stream>>>(Hb, WB_att + (size_t)l*ATT_S,
                                                                nullptr, BIG, ROWS, 3*DD, DD);
        attn_mfma6<<<dim3(BB*HH*32),256,0,stream>>>(BIG, Hb);
        gemm_mfma<1><<<dim3(DD/128, ROWS/128),256,0,stream>>>(Hb, WB_prj + (size_t)l*PRJ_S,
                                                              X, nullptr, ROWS, DD, DD);
        ln_kernel<<<ROWS,64,0,stream>>>(X, ln2_w, (size_t)l*DD, Hb, FLAG);
        gemm_mfma<2><<<dim3(4*DD/128, ROWS/128),256,0,stream>>>(Hb, WB_fc + (size_t)l*FC_S,
                                                                nullptr, BIG, ROWS, 4*DD, DD);
        gemm_mfma<1><<<dim3(DD/128, ROWS/128),256,0,stream>>>(BIG, WB_fcp + (size_t)l*FC_S,
                                                              X, nullptr, ROWS, DD, 4*DD);
    }
    ln_kernel<<<ROWS,64,0,stream>>>(X, lnf_w, 0, Hb, FLAG);
    gemm_nt3<<<dim3((VV+63)/64, ROWS/64),256,0,stream>>>(Hb, wte, 0, out, ROWS, VV, DD, FLAG);
    loss_kernel<<<ROWS,64,0,stream>>>(out, targets, ACC);
    fin_loss<<<1,1,0,stream>>>(ACC, out + (size_t)ROWS*VV);
}